// Round 6
// baseline (338.981 us; speedup 1.0000x reference)
//
#include <hip/hip_runtime.h>
#include <hip/hip_bf16.h>
#include <stdint.h>

// ---------- types ----------
typedef short bf16x8 __attribute__((ext_vector_type(8)));
typedef short bf16x4 __attribute__((ext_vector_type(4)));
typedef float f32x4  __attribute__((ext_vector_type(4)));

__device__ __forceinline__ float b2f(short s) {
  union { float f; uint32_t u; } x;
  x.u = ((uint32_t)(uint16_t)s) << 16;
  return x.f;
}
__device__ __forceinline__ short f2b(float f) {
  union { float f; uint32_t u; } x;
  x.f = f;
  uint32_t r = x.u + 0x7fff + ((x.u >> 16) & 1);  // RNE
  return (short)(r >> 16);
}

__device__ __forceinline__ void gload_lds16(const void* g, void* l) {
  __builtin_amdgcn_global_load_lds(
      (const __attribute__((address_space(1))) void*)g,
      (__attribute__((address_space(3))) void*)l, 16, 0, 0);
}

// ---------- prep: f32 -> bf16 conversions + rope tables ----------
__global__ __launch_bounds__(256)
void prep(const float* __restrict__ x, const float* __restrict__ rope,
          const float* __restrict__ wq, const float* __restrict__ wk,
          const float* __restrict__ wv, const float* __restrict__ wo,
          short* __restrict__ Xb, short* __restrict__ Wqkv, short* __restrict__ Wob,
          float* __restrict__ costab, float* __restrict__ sintab)
{
  const int64_t XN4 = 16777216 / 4;   // x float4 count
  const int64_t WN4 = 1048576 / 4;    // one weight matrix float4 count
  const int64_t total = XN4 + 4 * WN4 + 512;
  for (int64_t i = (int64_t)blockIdx.x * blockDim.x + threadIdx.x; i < total;
       i += (int64_t)gridDim.x * blockDim.x) {
    if (i < XN4) {
      f32x4 v = ((const f32x4*)x)[i];
      bf16x4 o;
#pragma unroll
      for (int j = 0; j < 4; ++j) o[j] = f2b(v[j]);
      ((bf16x4*)Xb)[i] = o;
    } else if (i < XN4 + 3 * WN4) {
      int64_t j = i - XN4;
      const float* src = (j < WN4) ? wq : ((j < 2 * WN4) ? wk : wv);
      int64_t jj = j & (WN4 - 1);
      f32x4 v = ((const f32x4*)src)[jj];
      bf16x4 o;
#pragma unroll
      for (int q = 0; q < 4; ++q) o[q] = f2b(v[q]);
      ((bf16x4*)Wqkv)[j] = o;
    } else if (i < XN4 + 4 * WN4) {
      int64_t j = i - XN4 - 3 * WN4;
      f32x4 v = ((const f32x4*)wo)[j];
      bf16x4 o;
#pragma unroll
      for (int q = 0; q < 4; ++q) o[q] = f2b(v[q]);
      ((bf16x4*)Wob)[j] = o;
    } else {
      int64_t j = i - XN4 - 4 * WN4;   // 0..511
      int pos = (int)(j >> 5), f = (int)(j & 31);
      float a = rope[pos * 32 + f];
      costab[j] = cosf(a);
      sintab[j] = sinf(a);
    }
  }
}

// ---------- latency-deep bf16 GEMM, C = A(MxK) * B^T (B stored [N][K]) ----------
// BM=BN=256, BK=32, 512 thr (8 waves 2Mx4N, 128x64 out/wave).
// 4 LDS buffers x (A 16K | B 16K) = 128 KiB; prefetch 3 tiles ahead; ONE
// vmcnt(8) per K-iter forcing tile kt+1 two full iterations after issue.
// 2 phases/iter, 16 MFMA each. 64B-row LDS, granule^=(row>>1)&3 swizzle
// (uniform bank coverage; r2/r5 measured 0 conflicts with the same family).
__device__ __forceinline__ void store4(short* C, size_t idx, f32x4 v) {
  bf16x4 o;
#pragma unroll
  for (int j = 0; j < 4; ++j) o[j] = f2b(v[j]);
  *(bf16x4*)(C + idx) = o;
}
__device__ __forceinline__ void store4(float* C, size_t idx, f32x4 v) {
  *(f32x4*)(C + idx) = v;
}

template <typename OutT>
__global__ __launch_bounds__(512, 2)
void gemm_bt4(const short* __restrict__ A, const short* __restrict__ Bw,
              OutT* __restrict__ C, int M, int N, int K, int nnt)
{
  __shared__ __align__(16) char lds[131072];   // 4 bufs x (A 16K | B 16K)
  const int t = threadIdx.x, lane = t & 63, wid = t >> 6;
  const int wm = wid >> 2, wn = wid & 3;       // 2M x 4N wave grid
  const int lr = lane & 15, ls = lane >> 4;

  const int nwg = gridDim.x, bid = blockIdx.x;
  const int swz = (bid & 7) * (nwg >> 3) + (bid >> 3);   // bijective (nwg%8==0)
  const int nt = swz % nnt, mt = swz / nnt;    // nt-fastest: A panel L2-resident
  const int m0 = mt << 8, n0 = nt << 8;
  const int T = K >> 5;                        // BK=32 tiles

  // staging: chunk = 1024B = 16 rows x 64B; lane l -> row c*16+(l>>2), slot l&3.
  // LDS(row,slot) must hold global granule slot^((row>>1)&3)  =>  per-lane
  // pre-swizzled source granule g = (l&3) ^ ((l>>3)&3).
  const int srow = lane >> 2;
  const int gsrc = (lane & 3) ^ ((lane >> 3) & 3);

  auto stageA = [&](int kt) {
    char* base = lds + (kt & 3) * 32768;
#pragma unroll
    for (int j = 0; j < 2; ++j) {
      int c = j * 8 + wid;                     // 16 chunks
      gload_lds16(A + (size_t)(m0 + c * 16 + srow) * K + (kt << 5) + (gsrc << 3),
                  base + c * 1024);
    }
  };
  auto stageB = [&](int kt) {
    char* base = lds + (kt & 3) * 32768 + 16384;
#pragma unroll
    for (int j = 0; j < 2; ++j) {
      int c = j * 8 + wid;
      gload_lds16(Bw + (size_t)(n0 + c * 16 + srow) * K + (kt << 5) + (gsrc << 3),
                  base + c * 1024);
    }
  };

  f32x4 acc[8][4];
#pragma unroll
  for (int m = 0; m < 8; ++m)
#pragma unroll
    for (int n = 0; n < 4; ++n) acc[m][n] = (f32x4){0.f, 0.f, 0.f, 0.f};

  const int ug = ((ls ^ ((lr >> 1) & 3)) & 3) * 16;   // swizzled 16B slot offset

  bf16x8 av[4], bv[4];
  auto ldA = [&](int kt, int half) {
    const char* base = lds + (kt & 3) * 32768;
#pragma unroll
    for (int i = 0; i < 4; ++i) {
      int row = wm * 128 + (half * 4 + i) * 16 + lr;
      av[i] = *(const bf16x8*)(base + row * 64 + ug);
    }
  };
  auto ldB = [&](int kt) {
    const char* base = lds + (kt & 3) * 32768 + 16384;
#pragma unroll
    for (int j = 0; j < 4; ++j) {
      int row = wn * 64 + j * 16 + lr;
      bv[j] = *(const bf16x8*)(base + row * 64 + ug);
    }
  };
  auto mfma16 = [&](int half) {
    __builtin_amdgcn_s_setprio(1);
#pragma unroll
    for (int i = 0; i < 4; ++i)
#pragma unroll
      for (int j = 0; j < 4; ++j)
        // swapped operands: D row = lane&15 (M), col = (lane>>4)*4+i (N)
        acc[half * 4 + i][j] = __builtin_amdgcn_mfma_f32_16x16x32_bf16(
            bv[j], av[i], acc[half * 4 + i][j], 0, 0, 0);
    __builtin_amdgcn_s_setprio(0);
  };

  // prologue: stage tiles 0,1,2 (12 loads); force tile 0 (leave 8 in flight)
  stageA(0); stageB(0); stageA(1); stageB(1); stageA(2); stageB(2);
  asm volatile("s_waitcnt vmcnt(8)" ::: "memory");
  __builtin_amdgcn_s_barrier();

  for (int kt = 0; kt < T; ++kt) {
    // ---- phase 0: a[0..3] x b[0..3] ----
    ldA(kt, 0); ldB(kt);                       // 8 ds_read_b128
    if (kt + 3 < T) stageA(kt + 3);            // 2 gload_lds
    __builtin_amdgcn_s_barrier();
    asm volatile("s_waitcnt lgkmcnt(0)" ::: "memory");
    __builtin_amdgcn_sched_barrier(0);
    mfma16(0);
    __builtin_amdgcn_s_barrier();
    // ---- phase 1: a[4..7] x b[0..3] (B kept in regs) ----
    ldA(kt, 1);                                // 4 ds_read_b128
    if (kt + 3 < T) {
      stageB(kt + 3);
      asm volatile("s_waitcnt vmcnt(8)" ::: "memory");   // forces tile kt+1
    } else if (kt + 2 < T) {
      asm volatile("s_waitcnt vmcnt(4)" ::: "memory");
    } else {
      asm volatile("s_waitcnt vmcnt(0)" ::: "memory");
    }
    __builtin_amdgcn_s_barrier();
    asm volatile("s_waitcnt lgkmcnt(0)" ::: "memory");
    __builtin_amdgcn_sched_barrier(0);
    mfma16(1);
    __builtin_amdgcn_s_barrier();
  }

  // epilogue: lane holds rows (lr + m4*16), 4 consecutive N-cols per acc
  const int orow = m0 + wm * 128 + lr;
  const int ocol = n0 + wn * 64 + ls * 4;
#pragma unroll
  for (int m4 = 0; m4 < 8; ++m4)
#pragma unroll
    for (int n4 = 0; n4 < 4; ++n4)
      store4(C, (size_t)(orow + m4 * 16) * N + (ocol + n4 * 16), acc[m4][n4]);
}

// ---------- windowed attention: one wave per (window, head) ----------
__global__ __launch_bounds__(256)
void attn_win(const short* __restrict__ QKV,   // [16384][3072] = q|k|v
              const float* __restrict__ costab, const float* __restrict__ sintab,
              short* __restrict__ Attn)        // [16384][1024]
{
  __shared__ float Plds[4][16][17];
  __shared__ short Vlds[4][16][64];
  const int t = threadIdx.x, lane = t & 63, wid = t >> 6;
  const int pair = blockIdx.x * 4 + wid;       // window*16 + head
  const int win = pair >> 4, h = pair & 15;
  const int lr = lane & 15;                    // token row within window
  const int lk = (lane >> 4) << 3;             // dim sub-offset 0,8,16,24

  const size_t rowb = (size_t)(win * 16 + lr) * 3072;
  const short* qp = QKV + rowb + h * 64;
  const short* kp = qp + 1024;

  bf16x8 q0 = *(const bf16x8*)(qp + lk);
  bf16x8 q1 = *(const bf16x8*)(qp + 32 + lk);
  bf16x8 k0 = *(const bf16x8*)(kp + lk);
  bf16x8 k1 = *(const bf16x8*)(kp + 32 + lk);

  // stage V tile [16][64] into LDS (2 x 16B per lane)
#pragma unroll
  for (int j = 0; j < 2; ++j) {
    int e = (j * 64 + lane) * 8;
    int vr = e >> 6, vc = e & 63;
    *(bf16x8*)&Vlds[wid][vr][vc] =
        *(const bf16x8*)(QKV + (size_t)(win * 16 + vr) * 3072 + 2048 + h * 64 + vc);
  }

  // in-register RoPE: pair (d, d+32) lives in (q0[j], q1[j]) of the same lane
  bf16x8 a0, a1, b0, b1;
#pragma unroll
  for (int j = 0; j < 8; ++j) {
    int f = lk + j;
    float c = costab[lr * 32 + f], s = sintab[lr * 32 + f];
    float x1 = b2f(q0[j]), x2 = b2f(q1[j]);
    a0[j] = f2b(x1 * c - x2 * s);
    a1[j] = f2b(x1 * s + x2 * c);
    float y1 = b2f(k0[j]), y2 = b2f(k1[j]);
    b0[j] = f2b(y1 * c - y2 * s);
    b1[j] = f2b(y1 * s + y2 * c);
  }

  // scores = q . k^T  (16x16, K=64 via two K=32 MFMAs)
  f32x4 sc = (f32x4){0.f, 0.f, 0.f, 0.f};
  sc = __builtin_amdgcn_mfma_f32_16x16x32_bf16(a0, b0, sc, 0, 0, 0);
  sc = __builtin_amdgcn_mfma_f32_16x16x32_bf16(a1, b1, sc, 0, 0, 0);

  // softmax over cols (col = lane&15; reduce across the 16-lane group)
  float p[4];
#pragma unroll
  for (int i = 0; i < 4; ++i) {
    float v = sc[i] * 0.125f;   // 1/sqrt(64)
    float m = v;
#pragma unroll
    for (int msk = 1; msk < 16; msk <<= 1) m = fmaxf(m, __shfl_xor(m, msk));
    float e = __expf(v - m);
    float s = e;
#pragma unroll
    for (int msk = 1; msk < 16; msk <<= 1) s += __shfl_xor(s, msk);
    p[i] = e / s;
  }
#pragma unroll
  for (int i = 0; i < 4; ++i)
    Plds[wid][((lane >> 4) << 2) + i][lr] = p[i];

  __syncthreads();

  // PV: lane owns (row r = lane&15, d-block = lane>>4), 16 outputs
  const int r = lr, dblk = lane >> 4;
  float a[16];
#pragma unroll
  for (int j = 0; j < 16; ++j) a[j] = 0.f;
#pragma unroll
  for (int k = 0; k < 16; ++k) {
    float pk = Plds[wid][r][k];
    bf16x8 v0 = *(const bf16x8*)&Vlds[wid][k][dblk * 16];
    bf16x8 v1 = *(const bf16x8*)&Vlds[wid][k][dblk * 16 + 8];
#pragma unroll
    for (int j = 0; j < 8; ++j) {
      a[j]     += pk * b2f(v0[j]);
      a[8 + j] += pk * b2f(v1[j]);
    }
  }
  bf16x8 o0, o1;
#pragma unroll
  for (int j = 0; j < 8; ++j) { o0[j] = f2b(a[j]); o1[j] = f2b(a[8 + j]); }
  short* op = Attn + (size_t)(win * 16 + r) * 1024 + h * 64 + dblk * 16;
  *(bf16x8*)op = o0;
  *(bf16x8*)(op + 8) = o1;
}

// ---------- launch ----------
extern "C" void kernel_launch(void* const* d_in, const int* in_sizes, int n_in,
                              void* d_out, int out_size, void* d_ws, size_t ws_size,
                              hipStream_t stream)
{
  const float* x  = (const float*)d_in[0];
  const float* rf = (const float*)d_in[1];
  const float* wq = (const float*)d_in[2];
  const float* wk = (const float*)d_in[3];
  const float* wv = (const float*)d_in[4];
  const float* wo = (const float*)d_in[5];
  float* out = (float*)d_out;

  char* w = (char*)d_ws;
  short* Xb     = (short*)(w);                          // 33,554,432 B
  short* Wqkv   = (short*)(w + 33554432);               //  6,291,456 B
  short* Wob    = (short*)(w + 39845888);               //  2,097,152 B
  short* QKV    = (short*)(w + 41943040);               // 100,663,296 B
  short* Attn   = (short*)(w + 142606336);              // 33,554,432 B
  float* costab = (float*)(w + 176160768);              // 2,048 B
  float* sintab = (float*)(w + 176162816);              // 2,048 B

  prep<<<2048, 256, 0, stream>>>(x, rf, wq, wk, wv, wo, Xb, Wqkv, Wob, costab, sintab);
  // QKV: M=16384 (64 mt), N=3072 (12 nt) -> 768 blocks (%8==0)
  gemm_bt4<short><<<768, 512, 0, stream>>>(Xb, Wqkv, QKV, 16384, 3072, 1024, 12);
  attn_win<<<4096, 256, 0, stream>>>(QKV, costab, sintab, Attn);
  // WO: M=16384 (64 mt), N=1024 (4 nt) -> 256 blocks (%8==0)
  gemm_bt4<float><<<256, 512, 0, stream>>>(Attn, Wob, out, 16384, 1024, 1024, 4);
}

// Round 8
// 326.003 us; speedup vs baseline: 1.0398x; 1.0398x over previous
//
#include <hip/hip_runtime.h>
#include <hip/hip_bf16.h>
#include <stdint.h>

// ---------- types ----------
typedef short bf16x8 __attribute__((ext_vector_type(8)));
typedef short bf16x4 __attribute__((ext_vector_type(4)));
typedef float f32x4  __attribute__((ext_vector_type(4)));

__device__ __forceinline__ float b2f(short s) {
  union { float f; uint32_t u; } x;
  x.u = ((uint32_t)(uint16_t)s) << 16;
  return x.f;
}
__device__ __forceinline__ short f2b(float f) {
  union { float f; uint32_t u; } x;
  x.f = f;
  uint32_t r = x.u + 0x7fff + ((x.u >> 16) & 1);  // RNE
  return (short)(r >> 16);
}

__device__ __forceinline__ void gload_lds16(const void* g, void* l) {
  __builtin_amdgcn_global_load_lds(
      (const __attribute__((address_space(1))) void*)g,
      (__attribute__((address_space(3))) void*)l, 16, 0, 0);
}

// ---------- prep: f32 -> bf16 conversions + rope tables ----------
__global__ __launch_bounds__(256)
void prep(const float* __restrict__ x, const float* __restrict__ rope,
          const float* __restrict__ wq, const float* __restrict__ wk,
          const float* __restrict__ wv, const float* __restrict__ wo,
          short* __restrict__ Xb, short* __restrict__ Wqkv, short* __restrict__ Wob,
          float* __restrict__ costab, float* __restrict__ sintab)
{
  const int64_t XN4 = 16777216 / 4;   // x float4 count
  const int64_t WN4 = 1048576 / 4;    // one weight matrix float4 count
  const int64_t total = XN4 + 4 * WN4 + 512;
  for (int64_t i = (int64_t)blockIdx.x * blockDim.x + threadIdx.x; i < total;
       i += (int64_t)gridDim.x * blockDim.x) {
    if (i < XN4) {
      f32x4 v = ((const f32x4*)x)[i];
      bf16x4 o;
#pragma unroll
      for (int j = 0; j < 4; ++j) o[j] = f2b(v[j]);
      ((bf16x4*)Xb)[i] = o;
    } else if (i < XN4 + 3 * WN4) {
      int64_t j = i - XN4;
      const float* src = (j < WN4) ? wq : ((j < 2 * WN4) ? wk : wv);
      int64_t jj = j & (WN4 - 1);
      f32x4 v = ((const f32x4*)src)[jj];
      bf16x4 o;
#pragma unroll
      for (int q = 0; q < 4; ++q) o[q] = f2b(v[q]);
      ((bf16x4*)Wqkv)[j] = o;
    } else if (i < XN4 + 4 * WN4) {
      int64_t j = i - XN4 - 3 * WN4;
      f32x4 v = ((const f32x4*)wo)[j];
      bf16x4 o;
#pragma unroll
      for (int q = 0; q < 4; ++q) o[q] = f2b(v[q]);
      ((bf16x4*)Wob)[j] = o;
    } else {
      int64_t j = i - XN4 - 4 * WN4;   // 0..511
      int pos = (int)(j >> 5), f = (int)(j & 31);
      float a = rope[pos * 32 + f];
      costab[j] = cosf(a);
      sintab[j] = sinf(a);
    }
  }
}

// ---------- K-half-phase bf16 GEMM, C = A(MxK) * B^T (B stored [N][K]) ----------
// BM=BN=256, BK=64, 512 thr (8 waves 2Mx4N, 128x64 out/wave).
// Phase (kt,p): read A/B K-half p of tile kt (12 ds_read_b128), stage K-half p
// of tile kt+1 (4 gload_lds), 32 MFMA (compiler interleaves via fine lgkmcnt),
// vmcnt(4), ONE s_barrier. No asm lgkmcnt, no sched_barrier (m141 lesson).
// LDS 128 KiB = 2 buf x [A0|A1|B0|B1] 16 KiB units. Zero-conflict swizzle (r6).
__device__ __forceinline__ void store4(short* C, size_t idx, f32x4 v) {
  bf16x4 o;
#pragma unroll
  for (int j = 0; j < 4; ++j) o[j] = f2b(v[j]);
  *(bf16x4*)(C + idx) = o;
}
__device__ __forceinline__ void store4(float* C, size_t idx, f32x4 v) {
  *(f32x4*)(C + idx) = v;
}

template <typename OutT>
__global__ __launch_bounds__(512, 2)
void gemm_bt5(const short* __restrict__ A, const short* __restrict__ Bw,
              OutT* __restrict__ C, int M, int N, int K, int nnt)
{
  __shared__ __align__(16) char lds[131072];   // buf b: b*65536 + {A0,A1,B0,B1}*16384
  const int t = threadIdx.x, lane = t & 63, wid = t >> 6;
  const int wm = wid >> 2, wn = wid & 3;       // 2M x 4N wave grid
  const int lr = lane & 15, ls = lane >> 4;

  const int nwg = gridDim.x, bid = blockIdx.x;
  const int swz = (bid & 7) * (nwg >> 3) + (bid >> 3);   // bijective (nwg%8==0)
  const int nt = swz % nnt, mt = swz / nnt;    // nt-fastest: A panel L2-resident
  const int m0 = mt << 8, n0 = nt << 8;
  const int T = K >> 6;                        // BK=64 tiles

  // staging: unit = [256 rows][32 K] bf16, 16 chunks of 1 KB (16 rows x 64 B).
  // lane -> row (lane>>2), granule (lane&3) pre-swizzled so LDS(row, g) holds
  // global granule g^((row>>1)&3).
  const int srow = lane >> 2;
  const int gsrc = (lane & 3) ^ ((lane >> 3) & 3);

  auto stage = [&](int kt, int p) {             // stage A-half p and B-half p
    char* ab = lds + (kt & 1) * 65536 + p * 16384;
    char* bb = ab + 32768;
    const int kcol = (kt << 6) + (p << 5) + (gsrc << 3);
#pragma unroll
    for (int j = 0; j < 2; ++j) {
      int c = j * 8 + wid;
      gload_lds16(A + (size_t)(m0 + c * 16 + srow) * K + kcol, ab + c * 1024);
    }
#pragma unroll
    for (int j = 0; j < 2; ++j) {
      int c = j * 8 + wid;
      gload_lds16(Bw + (size_t)(n0 + c * 16 + srow) * K + kcol, bb + c * 1024);
    }
  };

  f32x4 acc[8][4];
#pragma unroll
  for (int m = 0; m < 8; ++m)
#pragma unroll
    for (int n = 0; n < 4; ++n) acc[m][n] = (f32x4){0.f, 0.f, 0.f, 0.f};

  const int ug = ((ls ^ ((lr >> 1) & 3)) & 3) * 16;   // swizzled 16B slot

  auto run_phase = [&](int kt, int p) {
    const char* ab = lds + (kt & 1) * 65536 + p * 16384;
    const char* bb = ab + 32768;
    bf16x8 av[8], bv[4];
#pragma unroll
    for (int i = 0; i < 8; ++i)
      av[i] = *(const bf16x8*)(ab + (wm * 128 + i * 16 + lr) * 64 + ug);
#pragma unroll
    for (int j = 0; j < 4; ++j)
      bv[j] = *(const bf16x8*)(bb + (wn * 64 + j * 16 + lr) * 64 + ug);
    if (kt + 1 < T) stage(kt + 1, p);
    __builtin_amdgcn_s_setprio(1);
#pragma unroll
    for (int i = 0; i < 8; ++i)
#pragma unroll
      for (int j = 0; j < 4; ++j)
        // swapped operands: D row = lane&15 (M), col = (lane>>4)*4+reg (N)
        acc[i][j] = __builtin_amdgcn_mfma_f32_16x16x32_bf16(
            bv[j], av[i], acc[i][j], 0, 0, 0);
    __builtin_amdgcn_s_setprio(0);
    if (kt + 1 < T)      asm volatile("s_waitcnt vmcnt(4)" ::: "memory");
    else if (p == 0)     asm volatile("s_waitcnt vmcnt(0)" ::: "memory");
    __builtin_amdgcn_s_barrier();
  };

  // prologue: stage both K-halves of tile 0; force half 0; barrier
  stage(0, 0); stage(0, 1);
  asm volatile("s_waitcnt vmcnt(4)" ::: "memory");
  __builtin_amdgcn_s_barrier();

  for (int kt = 0; kt < T; ++kt) {
    run_phase(kt, 0);
    run_phase(kt, 1);
  }

  // epilogue: lane holds rows (lr + m4*16), 4 consecutive N-cols per acc
  const int orow = m0 + wm * 128 + lr;
  const int ocol = n0 + wn * 64 + ls * 4;
#pragma unroll
  for (int m4 = 0; m4 < 8; ++m4)
#pragma unroll
    for (int n4 = 0; n4 < 4; ++n4)
      store4(C, (size_t)(orow + m4 * 16) * N + (ocol + n4 * 16), acc[m4][n4]);
}

// ---------- windowed attention: one wave per (window, head) ----------
__global__ __launch_bounds__(256)
void attn_win(const short* __restrict__ QKV,   // [16384][3072] = q|k|v
              const float* __restrict__ costab, const float* __restrict__ sintab,
              short* __restrict__ Attn)        // [16384][1024]
{
  __shared__ float Plds[4][16][17];
  __shared__ short Vlds[4][16][64];
  const int t = threadIdx.x, lane = t & 63, wid = t >> 6;
  const int pair = blockIdx.x * 4 + wid;       // window*16 + head
  const int win = pair >> 4, h = pair & 15;
  const int lr = lane & 15;                    // token row within window
  const int lk = (lane >> 4) << 3;             // dim sub-offset 0,8,16,24

  const size_t rowb = (size_t)(win * 16 + lr) * 3072;
  const short* qp = QKV + rowb + h * 64;
  const short* kp = qp + 1024;

  bf16x8 q0 = *(const bf16x8*)(qp + lk);
  bf16x8 q1 = *(const bf16x8*)(qp + 32 + lk);
  bf16x8 k0 = *(const bf16x8*)(kp + lk);
  bf16x8 k1 = *(const bf16x8*)(kp + 32 + lk);

  // stage V tile [16][64] into LDS (2 x 16B per lane)
#pragma unroll
  for (int j = 0; j < 2; ++j) {
    int e = (j * 64 + lane) * 8;
    int vr = e >> 6, vc = e & 63;
    *(bf16x8*)&Vlds[wid][vr][vc] =
        *(const bf16x8*)(QKV + (size_t)(win * 16 + vr) * 3072 + 2048 + h * 64 + vc);
  }

  // in-register RoPE: pair (d, d+32) lives in (q0[j], q1[j]) of the same lane
  bf16x8 a0, a1, b0, b1;
#pragma unroll
  for (int j = 0; j < 8; ++j) {
    int f = lk + j;
    float c = costab[lr * 32 + f], s = sintab[lr * 32 + f];
    float x1 = b2f(q0[j]), x2 = b2f(q1[j]);
    a0[j] = f2b(x1 * c - x2 * s);
    a1[j] = f2b(x1 * s + x2 * c);
    float y1 = b2f(k0[j]), y2 = b2f(k1[j]);
    b0[j] = f2b(y1 * c - y2 * s);
    b1[j] = f2b(y1 * s + y2 * c);
  }

  // scores = q . k^T  (16x16, K=64 via two K=32 MFMAs)
  f32x4 sc = (f32x4){0.f, 0.f, 0.f, 0.f};
  sc = __builtin_amdgcn_mfma_f32_16x16x32_bf16(a0, b0, sc, 0, 0, 0);
  sc = __builtin_amdgcn_mfma_f32_16x16x32_bf16(a1, b1, sc, 0, 0, 0);

  // softmax over cols (col = lane&15; reduce across the 16-lane group)
  float p[4];
#pragma unroll
  for (int i = 0; i < 4; ++i) {
    float v = sc[i] * 0.125f;   // 1/sqrt(64)
    float m = v;
#pragma unroll
    for (int msk = 1; msk < 16; msk <<= 1) m = fmaxf(m, __shfl_xor(m, msk));
    float e = __expf(v - m);
    float s = e;
#pragma unroll
    for (int msk = 1; msk < 16; msk <<= 1) s += __shfl_xor(s, msk);
    p[i] = e / s;
  }
#pragma unroll
  for (int i = 0; i < 4; ++i)
    Plds[wid][((lane >> 4) << 2) + i][lr] = p[i];

  __syncthreads();

  // PV: lane owns (row r = lane&15, d-block = lane>>4), 16 outputs
  const int r = lr, dblk = lane >> 4;
  float a[16];
#pragma unroll
  for (int j = 0; j < 16; ++j) a[j] = 0.f;
#pragma unroll
  for (int k = 0; k < 16; ++k) {
    float pk = Plds[wid][r][k];
    bf16x8 v0 = *(const bf16x8*)&Vlds[wid][k][dblk * 16];
    bf16x8 v1 = *(const bf16x8*)&Vlds[wid][k][dblk * 16 + 8];
#pragma unroll
    for (int j = 0; j < 8; ++j) {
      a[j]     += pk * b2f(v0[j]);
      a[8 + j] += pk * b2f(v1[j]);
    }
  }
  bf16x8 o0, o1;
#pragma unroll
  for (int j = 0; j < 8; ++j) { o0[j] = f2b(a[j]); o1[j] = f2b(a[8 + j]); }
  short* op = Attn + (size_t)(win * 16 + r) * 1024 + h * 64 + dblk * 16;
  *(bf16x8*)op = o0;
  *(bf16x8*)(op + 8) = o1;
}

// ---------- launch ----------
extern "C" void kernel_launch(void* const* d_in, const int* in_sizes, int n_in,
                              void* d_out, int out_size, void* d_ws, size_t ws_size,
                              hipStream_t stream)
{
  const float* x  = (const float*)d_in[0];
  const float* rf = (const float*)d_in[1];
  const float* wq = (const float*)d_in[2];
  const float* wk = (const float*)d_in[3];
  const float* wv = (const float*)d_in[4];
  const float* wo = (const float*)d_in[5];
  float* out = (float*)d_out;

  char* w = (char*)d_ws;
  short* Xb     = (short*)(w);                          // 33,554,432 B
  short* Wqkv   = (short*)(w + 33554432);               //  6,291,456 B
  short* Wob    = (short*)(w + 39845888);               //  2,097,152 B
  short* QKV    = (short*)(w + 41943040);               // 100,663,296 B
  short* Attn   = (short*)(w + 142606336);              // 33,554,432 B
  float* costab = (float*)(w + 176160768);              // 2,048 B
  float* sintab = (float*)(w + 176162816);              // 2,048 B

  prep<<<2048, 256, 0, stream>>>(x, rf, wq, wk, wv, wo, Xb, Wqkv, Wob, costab, sintab);
  // QKV: M=16384 (64 mt), N=3072 (12 nt) -> 768 blocks (%8==0)
  gemm_bt5<short><<<768, 512, 0, stream>>>(Xb, Wqkv, QKV, 16384, 3072, 1024, 12);
  attn_win<<<4096, 256, 0, stream>>>(QKV, costab, sintab, Attn);
  // WO: M=16384 (64 mt), N=1024 (4 nt) -> 256 blocks (%8==0)
  gemm_bt5<float><<<256, 512, 0, stream>>>(Attn, Wob, out, 16384, 1024, 1024, 4);
}